// Round 6
// baseline (412.681 us; speedup 1.0000x reference)
//
#include <hip/hip_runtime.h>
#include <hip/hip_bf16.h>

#define IDIM 1771
#define NF 64
#define NG 512

constexpr int OFFS[12] = {0, 1, 10, 35, 84, 165, 286, 455, 680, 969, 1330, 1771};

typedef float f32x4 __attribute__((ext_vector_type(4)));
typedef float f32x2 __attribute__((ext_vector_type(2)));
typedef __bf16 bf16x2 __attribute__((ext_vector_type(2)));
typedef __bf16 bf16x8 __attribute__((ext_vector_type(8)));

__device__ __forceinline__ void gl_lds16(const void* g, void* l) {
    __builtin_amdgcn_global_load_lds((const __attribute__((address_space(1))) void*)g,
                                     (__attribute__((address_space(3))) void*)l, 16, 0, 0);
}

// ---------------------------------------------------------------------------
// prep_dw: blk 0..223 transpose D -> Dt bf16; blk 224..287 w -> wb bf16.
// ---------------------------------------------------------------------------
__global__ __launch_bounds__(256) void prep_dw_kernel(const float* __restrict__ D,
                                                      const float* __restrict__ w,
                                                      __bf16* __restrict__ Dt,
                                                      __bf16* __restrict__ wb) {
    __shared__ alignas(16) float T[64][65];
    const int blk = blockIdx.x;
    const int t = threadIdx.x;
    const int lane = t & 63, grp = t >> 6;

    if (blk < 224) {
        const int ct = blk >> 3, nt = blk & 7;
        const int c0 = ct * 64, n0 = nt * 64;
        float tmp[16];
#pragma unroll
        for (int p = 0; p < 16; ++p) {
            int nn = grp + p * 4;
            int c = c0 + lane;
            tmp[p] = (c < IDIM) ? D[(size_t)(n0 + nn) * IDIM + c] : 0.0f;
        }
#pragma unroll
        for (int p = 0; p < 16; ++p) T[grp + p * 4][lane] = tmp[p];
        __syncthreads();
        for (int cc = grp; cc < 64; cc += 4) {
            int c = c0 + cc;
            if (c < IDIM) Dt[c * NG + n0 + lane] = (__bf16)T[lane][cc];
        }
    } else {
        const int o = blk - 224;
#pragma unroll
        for (int ii0 = 0; ii0 < 64; ii0 += 8) {
            f32x2 tmp[8];
#pragma unroll
            for (int j = 0; j < 8; ++j)
                tmp[j] = *(const f32x2*)&w[((size_t)((ii0 + j) * 64 + o)) * NG + t * 2];
#pragma unroll
            for (int j = 0; j < 8; ++j) {
                bf16x2 ov;
                ov.x = (__bf16)tmp[j].x;
                ov.y = (__bf16)tmp[j].y;
                *(bf16x2*)&wb[((size_t)(o * 64 + ii0 + j)) * NG + t * 2] = ov;
            }
        }
    }
}

// ---------------------------------------------------------------------------
// repack_x -> FRAGMENT-NATIVE A layout. Element (row r = b*d+m, k = u*64+i)
// lives at  16384*off + ((r>>4)*d + u)*1024 + (i>>3)*128 + (r&15)*8 + (i&7),
// so a gemm wave's 16B fragment is 64-lane contiguous (1KB per load instr).
// ---------------------------------------------------------------------------
__global__ __launch_bounds__(256) void repack_x_kernel(const float* __restrict__ x,
                                                       __bf16* __restrict__ A) {
    __shared__ alignas(16) __bf16 T[64][66];
    const int idx = blockIdx.x;
    const int l = idx >> 8;        // 0..10
    const int b = idx & 255;       // 0..255
    const int t = threadIdx.x;
    const int lane = t & 63, grp = t >> 6;
    const int d = 2 * l + 1, off = OFFS[l], csq = d * d;
    const float* xb = x + (size_t)b * NF * IDIM + off;
    __bf16* Al = A + (size_t)16384 * off;

    for (int c0 = 0; c0 < csq; c0 += 64) {
        float tmp[16];
#pragma unroll
        for (int p = 0; p < 16; ++p) {
            int ii = grp + p * 4;
            int c = c0 + lane;
            tmp[p] = (c < csq) ? xb[(size_t)ii * IDIM + c] : 0.0f;
        }
#pragma unroll
        for (int p = 0; p < 16; ++p) T[grp + p * 4][lane] = (__bf16)tmp[p];
        __syncthreads();
#pragma unroll
        for (int s = 0; s < 2; ++s) {
            int idx2 = s * 256 + t;
            int c_loc = idx2 >> 3, i0 = (idx2 & 7) * 8;
            int c = c0 + c_loc;
            if (c < csq) {
                int u = (unsigned)c / (unsigned)d;
                int m = c - u * d;
                int r = b * d + m;
                bf16x8 v;
#pragma unroll
                for (int j = 0; j < 8; ++j) v[j] = T[i0 + j][c_loc];
                *(bf16x8*)(Al + (size_t)((r >> 4) * d + u) * 1024 +
                           (i0 >> 3) * 128 + (r & 15) * 8) = v;
            }
        }
        __syncthreads();
    }
}

// ---------------------------------------------------------------------------
// psi GEMM: interior identical to round-3 (BK=64, 2-stage dbuf, XOR swizzle).
// Epilogue now writes FRAGMENT-NATIVE Bm: element (col = o*d+v, k = u*64+i)
// at  4096*off + ((col>>4)*d + u)*1024 + (i>>3)*128 + (col&15)*8 + (i&7).
// ---------------------------------------------------------------------------
__global__ __launch_bounds__(256) void psi_mfma_kernel(const __bf16* __restrict__ Dt,
                                                       const __bf16* __restrict__ wb,
                                                       __bf16* __restrict__ Bm) {
    __shared__ alignas(16) __bf16 S[2 * 16384];  // 64KB

    const int t = threadIdx.x, w = t >> 6, ln = t & 63;
    const int row0 = blockIdx.x * 128;  // c
    const int col0 = blockIdx.y * 128;  // io'

    const bool isA = (w < 2);
    const int wsub = w & 1;
    const int rowloc = ln >> 3;
    const int logslot = (ln & 7) ^ rowloc;

    const __bf16* gp[8];
    __bf16* lp[8];
#pragma unroll
    for (int q = 0; q < 8; ++q) {
        int chunk = wsub * 8 + q;
        int row = chunk * 8 + rowloc;
        int g = isA ? (row0 + row < IDIM ? row0 + row : IDIM - 1) : (col0 + row);
        gp[q] = (isA ? Dt : wb) + (size_t)g * NG + logslot * 8;
        lp[q] = S + (isA ? 0 : 8192) + chunk * 512;
    }

    f32x4 acc[4][4];
    f32x4 zero = {0.0f, 0.0f, 0.0f, 0.0f};
#pragma unroll
    for (int i = 0; i < 4; ++i)
#pragma unroll
        for (int j = 0; j < 4; ++j) acc[i][j] = zero;

    const int wr = (w >> 1) * 64, wc = (w & 1) * 64;
    const int fr = ln & 15, kh = ln >> 4;
    const int fx = fr & 7;

    int aoff[2][4], boff[2][4];
#pragma unroll
    for (int kk = 0; kk < 2; ++kk)
#pragma unroll
        for (int mt = 0; mt < 4; ++mt) {
            aoff[kk][mt] = (wr + mt * 16 + fr) * 64 + (((kk << 2) | kh) ^ fx) * 8;
            boff[kk][mt] = (wc + mt * 16 + fr) * 64 + (((kk << 2) | kh) ^ fx) * 8;
        }

    const int np = NG / 64;  // 8

#pragma unroll
    for (int q = 0; q < 8; ++q) { gl_lds16(gp[q], lp[q]); gp[q] += 64; }
    asm volatile("s_waitcnt vmcnt(0)" ::: "memory");
    __builtin_amdgcn_s_barrier();
    __builtin_amdgcn_sched_barrier(0);

    int bi = 0;
    for (int p = 0; p < np; ++p) {
        if (p + 1 < np) {
#pragma unroll
            for (int q = 0; q < 8; ++q) {
                gl_lds16(gp[q], lp[q] + (bi ^ 1) * 16384);
                gp[q] += 64;
            }
        }
        const __bf16* As_ = S + bi * 16384;
        const __bf16* Bs_ = As_ + 8192;
        bf16x8 af[2][4], bf_[2][4];
#pragma unroll
        for (int kk = 0; kk < 2; ++kk) {
#pragma unroll
            for (int mt = 0; mt < 4; ++mt) af[kk][mt] = *(const bf16x8*)&As_[aoff[kk][mt]];
#pragma unroll
            for (int nt = 0; nt < 4; ++nt) bf_[kk][nt] = *(const bf16x8*)&Bs_[boff[kk][nt]];
        }
#pragma unroll
        for (int kk = 0; kk < 2; ++kk)
#pragma unroll
            for (int mt = 0; mt < 4; ++mt)
#pragma unroll
                for (int nt = 0; nt < 4; ++nt)
                    acc[mt][nt] = __builtin_amdgcn_mfma_f32_16x16x32_bf16(
                        af[kk][mt], bf_[kk][nt], acc[mt][nt], 0, 0, 0);
        asm volatile("s_waitcnt vmcnt(0)" ::: "memory");
        __builtin_amdgcn_s_barrier();
        __builtin_amdgcn_sched_barrier(0);
        bi ^= 1;
    }

    const float sc = 0.04419417382415922f;  // 1/sqrt(512)
    const int o = (col0 + wc) >> 6;         // wave-uniform
#pragma unroll
    for (int mt = 0; mt < 4; ++mt) {
#pragma unroll
        for (int e = 0; e < 4; ++e) {
            int c = row0 + wr + mt * 16 + kh * 4 + e;
            if (c < IDIM) {
                int l = 0;
#pragma unroll
                for (int ll = 1; ll < 11; ++ll)
                    if (c >= OFFS[ll]) l = ll;
                int d = 2 * l + 1, off = OFFS[l];
                int rem = c - off;
                int u = (unsigned)rem / (unsigned)d;
                int v = rem - u * d;
                int col = o * d + v;
                __bf16* bb = Bm + (size_t)4096 * off +
                             (size_t)((col >> 4) * d + u) * 1024 + (col & 15) * 8;
#pragma unroll
                for (int nt = 0; nt < 4; ++nt) {
                    int i = nt * 16 + fr;
                    bb[(i >> 3) * 128 + (i & 7)] = (__bf16)(acc[mt][nt][e] * sc);
                }
            }
        }
    }
}

// ---------------------------------------------------------------------------
// Stage-2 GEMM, barrier-free: fragment-native A and Bm are loaded DIRECTLY
// into registers (64-lane-contiguous 1KB per load), register double-buffered
// across K-steps. No LDS staging, no s_barrier, no vmcnt drains.
// ---------------------------------------------------------------------------
__global__ __launch_bounds__(256) void so3_gemm_all(const __bf16* __restrict__ A,
                                                    const __bf16* __restrict__ Bm,
                                                    float* __restrict__ out) {
    const int bid = blockIdx.x;
    const int v_ = (bid & 7) * 237 + (bid >> 3);  // grid 1896 = 8*237
    if (v_ >= 1892) return;

    int l = 10, base = 0;
    if (v_ >= 462)  { l = 9; base = 462; }
    if (v_ >= 842)  { l = 8; base = 842; }
    if (v_ >= 1148) { l = 7; base = 1148; }
    if (v_ >= 1388) { l = 6; base = 1388; }
    if (v_ >= 1570) { l = 5; base = 1570; }
    if (v_ >= 1702) { l = 4; base = 1702; }
    if (v_ >= 1792) { l = 3; base = 1792; }
    if (v_ >= 1848) { l = 2; base = 1848; }
    if (v_ >= 1878) { l = 1; base = 1878; }
    if (v_ >= 1890) { l = 0; base = 1890; }

    const int d = 2 * l + 1;
    const int off = OFFS[l];
    const int Np = 64 * d;
    const int ntiles = l + 1;
    const int rel = v_ - base;
    const int bx = (unsigned)rel / (unsigned)ntiles;
    const int by = rel - bx * ntiles;
    const int row0 = bx * 128, col0 = by * 128;

    constexpr float ALPHA[11] = {0.125f, 0.07216878f, 0.05590170f, 0.04724556f,
                                 0.04166667f, 0.03768892f, 0.03466879f, 0.03227486f,
                                 0.03031695f, 0.02867697f, 0.02727724f};

    __shared__ alignas(16) float TwS[4][256];  // epilogue transpose only (4KB)

    const int t = threadIdx.x, w = t >> 6, ln = t & 63;
    const int wr = (w >> 1) * 64, wc = (w & 1) * 64;
    const int fr = ln & 15, kh = ln >> 4;

    // per-lane fragment base pointers (fragment-native layouts)
    const int rT0 = (row0 + wr) >> 4;
    const int cT0 = (col0 + wc) >> 4;
    const __bf16* pA[4];
    const __bf16* pB[4];
#pragma unroll
    for (int mt = 0; mt < 4; ++mt)
        pA[mt] = A + (size_t)16384 * off + (size_t)(rT0 + mt) * d * 1024 + kh * 128 + fr * 8;
#pragma unroll
    for (int nt = 0; nt < 4; ++nt) {
        int cT = cT0 + nt;
        int cmax = 4 * d - 1;
        if (cT > cmax) cT = cmax;  // padded cols: valid addr, result discarded
        pB[nt] = Bm + (size_t)4096 * off + (size_t)cT * d * 1024 + kh * 128 + fr * 8;
    }

    f32x4 acc[4][4];
    f32x4 zero = {0.0f, 0.0f, 0.0f, 0.0f};
#pragma unroll
    for (int i = 0; i < 4; ++i)
#pragma unroll
        for (int j = 0; j < 4; ++j) acc[i][j] = zero;

    bf16x8 a0[2][4], b0[2][4], a1[2][4], b1[2][4];
#pragma unroll
    for (int kk = 0; kk < 2; ++kk)
#pragma unroll
        for (int q = 0; q < 4; ++q) {
            a0[kk][q] = *(const bf16x8*)(pA[q] + kk * 512);
            b0[kk][q] = *(const bf16x8*)(pB[q] + kk * 512);
        }

    const int np = d;  // K-steps of 64
    for (int p = 0; p < np; p += 2) {
        const bool has1 = (p + 1 < np), has2 = (p + 2 < np);
        if (has1) {
#pragma unroll
            for (int kk = 0; kk < 2; ++kk)
#pragma unroll
                for (int q = 0; q < 4; ++q) {
                    a1[kk][q] = *(const bf16x8*)(pA[q] + 1024 + kk * 512);
                    b1[kk][q] = *(const bf16x8*)(pB[q] + 1024 + kk * 512);
                }
        }
#pragma unroll
        for (int kk = 0; kk < 2; ++kk)
#pragma unroll
            for (int mt = 0; mt < 4; ++mt)
#pragma unroll
                for (int nt = 0; nt < 4; ++nt)
                    acc[mt][nt] = __builtin_amdgcn_mfma_f32_16x16x32_bf16(
                        a0[kk][mt], b0[kk][nt], acc[mt][nt], 0, 0, 0);
#pragma unroll
        for (int q = 0; q < 4; ++q) { pA[q] += 2048; pB[q] += 2048; }
        if (has2) {
#pragma unroll
            for (int kk = 0; kk < 2; ++kk)
#pragma unroll
                for (int q = 0; q < 4; ++q) {
                    a0[kk][q] = *(const bf16x8*)(pA[q] + kk * 512);
                    b0[kk][q] = *(const bf16x8*)(pB[q] + kk * 512);
                }
        }
        if (has1) {
#pragma unroll
            for (int kk = 0; kk < 2; ++kk)
#pragma unroll
                for (int mt = 0; mt < 4; ++mt)
#pragma unroll
                    for (int nt = 0; nt < 4; ++nt)
                        acc[mt][nt] = __builtin_amdgcn_mfma_f32_16x16x32_bf16(
                            a1[kk][mt], b1[kk][nt], acc[mt][nt], 0, 0, 0);
        }
    }

    // ---- epilogue: per-wave LDS reorder so stores run contiguous along m ----
    float* Tw = &TwS[w][0];  // private per wave: no barrier needed
    const float alpha = ALPHA[l];

#pragma unroll
    for (int mt = 0; mt < 4; ++mt) {
        int r = row0 + wr + mt * 16 + fr;
        int b = (unsigned)r / (unsigned)d;
        int m = r - b * d;
        float* ob = out + (size_t)b * NF * IDIM + off + m;
#pragma unroll
        for (int nt = 0; nt < 4; ++nt) {
#pragma unroll
            for (int e = 0; e < 4; ++e) Tw[(kh * 4 + e) * 16 + fr] = acc[mt][nt][e];
            f32x4 vals = *(const f32x4*)&Tw[fr * 16 + kh * 4];
            int qb = col0 + wc + nt * 16 + kh * 4;
            int o = (unsigned)qb / (unsigned)d;
            int vv = qb - o * d;
#pragma unroll
            for (int j = 0; j < 4; ++j) {
                if (qb + j < Np) ob[o * IDIM + vv * d] = alpha * vals[j];
                ++vv;
                if (vv == d) { vv = 0; ++o; }
            }
        }
    }
}

// ---------------------------------------------------------------------------
extern "C" void kernel_launch(void* const* d_in, const int* in_sizes, int n_in,
                              void* d_out, int out_size, void* d_ws, size_t ws_size,
                              hipStream_t stream) {
    const float* x = (const float*)d_in[0];   // (256, 64, 1771)
    const float* D = (const float*)d_in[1];   // (512, 1771)
    const float* w = (const float*)d_in[2];   // (64, 64, 512)
    float* out = (float*)d_out;               // (256, 64, 1771)

    char* ws = (char*)d_ws;
    const size_t DT_BYTES = (size_t)IDIM * NG * 2;        // 1,813,504
    const size_t WB_BYTES = (size_t)4096 * NG * 2;        // 4,194,304
    const size_t A_BYTES = (size_t)16384 * IDIM * 2;      // 58,032,128

    __bf16* Dt = (__bf16*)ws;
    __bf16* wb = (__bf16*)(ws + DT_BYTES);
    __bf16* A = (__bf16*)(ws + DT_BYTES + WB_BYTES);
    __bf16* Bm = (__bf16*)(ws + DT_BYTES + WB_BYTES + A_BYTES);

    prep_dw_kernel<<<288, 256, 0, stream>>>(D, w, Dt, wb);
    repack_x_kernel<<<2816, 256, 0, stream>>>(x, A);
    psi_mfma_kernel<<<dim3(14, 32), 256, 0, stream>>>(Dt, wb, Bm);
    so3_gemm_all<<<1896, 256, 0, stream>>>((const __bf16*)A, Bm, out);
}

// Round 7
// 376.151 us; speedup vs baseline: 1.0971x; 1.0971x over previous
//
#include <hip/hip_runtime.h>
#include <hip/hip_bf16.h>

#define IDIM 1771
#define NF 64
#define NG 512

constexpr int OFFS[12] = {0, 1, 10, 35, 84, 165, 286, 455, 680, 969, 1330, 1771};

typedef float f32x4 __attribute__((ext_vector_type(4)));
typedef float f32x2 __attribute__((ext_vector_type(2)));
typedef __bf16 bf16x2 __attribute__((ext_vector_type(2)));
typedef __bf16 bf16x8 __attribute__((ext_vector_type(8)));

__device__ __forceinline__ void gl_lds16(const void* g, void* l) {
    __builtin_amdgcn_global_load_lds((const __attribute__((address_space(1))) void*)g,
                                     (__attribute__((address_space(3))) void*)l, 16, 0, 0);
}

// ---------------------------------------------------------------------------
// Fused prep + repack (one launch, independent work):
//  blk 0..223   : transpose D (512,1771) f32 -> Dt (1771,512) bf16
//  blk 224..287 : transpose-cast w[i][o][n] f32 -> wb[o][i][n] bf16
//  blk 288..3103: repack x -> A[r=b*d+m][k=u*64+i] bf16 (row-major, stride Kp)
// repack LDS tile is [c][i] so phase-2 reads are CONTIGUOUS b32 (2-way
// aliasing = free) instead of 16 scalar 8-way-conflicted u16 reads.
// ---------------------------------------------------------------------------
__global__ __launch_bounds__(256) void prep_repack_kernel(const float* __restrict__ D,
                                                          const float* __restrict__ w,
                                                          const float* __restrict__ x,
                                                          __bf16* __restrict__ Dt,
                                                          __bf16* __restrict__ wb,
                                                          __bf16* __restrict__ A) {
    __shared__ alignas(16) char smem[16640];
    const int blk = blockIdx.x;
    const int t = threadIdx.x;
    const int lane = t & 63, grp = t >> 6;

    if (blk < 224) {
        // D transpose
        float (*T)[65] = (float (*)[65])smem;
        const int ct = blk >> 3, nt = blk & 7;
        const int c0 = ct * 64, n0 = nt * 64;
        float tmp[16];
#pragma unroll
        for (int p = 0; p < 16; ++p) {
            int nn = grp + p * 4;
            int c = c0 + lane;
            tmp[p] = (c < IDIM) ? D[(size_t)(n0 + nn) * IDIM + c] : 0.0f;
        }
#pragma unroll
        for (int p = 0; p < 16; ++p) T[grp + p * 4][lane] = tmp[p];
        __syncthreads();
        for (int cc = grp; cc < 64; cc += 4) {
            int c = c0 + cc;
            if (c < IDIM) Dt[c * NG + n0 + lane] = (__bf16)T[lane][cc];
        }
    } else if (blk < 288) {
        // w transpose-cast: wb[o][i][n] = bf16(w[i][o][n])
        const int o = blk - 224;
#pragma unroll
        for (int ii0 = 0; ii0 < 64; ii0 += 8) {
            f32x2 tmp[8];
#pragma unroll
            for (int j = 0; j < 8; ++j)
                tmp[j] = *(const f32x2*)&w[((size_t)((ii0 + j) * 64 + o)) * NG + t * 2];
#pragma unroll
            for (int j = 0; j < 8; ++j) {
                bf16x2 ov;
                ov.x = (__bf16)tmp[j].x;
                ov.y = (__bf16)tmp[j].y;
                *(bf16x2*)&wb[((size_t)(o * 64 + ii0 + j)) * NG + t * 2] = ov;
            }
        }
    } else {
        // repack x: A[(b*d+m)*Kp + u*64 + i] = bf16(x[b][i][off+u*d+m])
        const int idx = blk - 288;
        const int l = idx >> 8;        // 0..10
        const int b = idx & 255;       // 0..255
        const int d = 2 * l + 1, off = OFFS[l], csq = d * d, Kp = 64 * d;
        __bf16 (*T)[66] = (__bf16 (*)[66])smem;  // [c=64][i=66 padded]
        const float* xb = x + (size_t)b * NF * IDIM + off;
        __bf16* Ab = A + (size_t)16384 * off + (size_t)b * d * Kp;

        for (int c0 = 0; c0 < csq; c0 += 64) {
            // phase 1: 16 coalesced f32 loads (consecutive i per thread),
            // then 8 paired b32 LDS writes into T[c][i] (conflict-free)
            float tmp[16];
#pragma unroll
            for (int p = 0; p < 16; ++p) {
                int ii = grp * 16 + p;
                int c = c0 + lane;
                tmp[p] = (c < csq) ? xb[(size_t)ii * IDIM + c] : 0.0f;
            }
#pragma unroll
            for (int p2 = 0; p2 < 8; ++p2) {
                bf16x2 v;
                v.x = (__bf16)tmp[2 * p2];
                v.y = (__bf16)tmp[2 * p2 + 1];
                *(bf16x2*)&T[lane][grp * 16 + 2 * p2] = v;
            }
            __syncthreads();
            // phase 2: contiguous b32 reads from T[c][i0..i0+7] -> one 16B store
#pragma unroll
            for (int s = 0; s < 2; ++s) {
                int idx2 = s * 256 + t;
                int c_loc = idx2 >> 3, i0 = (idx2 & 7) * 8;
                int c = c0 + c_loc;
                if (c < csq) {
                    int u = (unsigned)c / (unsigned)d;
                    int m = c - u * d;
                    bf16x8 v;
#pragma unroll
                    for (int j2 = 0; j2 < 4; ++j2) {
                        bf16x2 r = *(const bf16x2*)&T[c_loc][i0 + 2 * j2];
                        v[2 * j2] = r.x;
                        v[2 * j2 + 1] = r.y;
                    }
                    *(bf16x8*)(Ab + (size_t)m * Kp + u * 64 + i0) = v;
                }
            }
            __syncthreads();
        }
    }
}

// ---------------------------------------------------------------------------
// psi GEMM: BK=64 fat phases, 2-stage dbuf, min-2-phase schedule, XOR slot
// swizzle (pre-swizzled global source, linear LDS dest, swizzled read).
// Identical to the verified round-3 kernel.
// ---------------------------------------------------------------------------
__global__ __launch_bounds__(256) void psi_mfma_kernel(const __bf16* __restrict__ Dt,
                                                       const __bf16* __restrict__ wb,
                                                       __bf16* __restrict__ Bm) {
    __shared__ alignas(16) __bf16 S[2 * 16384];  // 64KB

    const int t = threadIdx.x, w = t >> 6, ln = t & 63;
    const int row0 = blockIdx.x * 128;  // c
    const int col0 = blockIdx.y * 128;  // io'

    const bool isA = (w < 2);
    const int wsub = w & 1;
    const int rowloc = ln >> 3;             // 0..7
    const int logslot = (ln & 7) ^ rowloc;  // swizzled source k-slot

    const __bf16* gp[8];
    __bf16* lp[8];
#pragma unroll
    for (int q = 0; q < 8; ++q) {
        int chunk = wsub * 8 + q;           // 0..15
        int row = chunk * 8 + rowloc;       // 0..127
        int g = isA ? (row0 + row < IDIM ? row0 + row : IDIM - 1) : (col0 + row);
        gp[q] = (isA ? Dt : wb) + (size_t)g * NG + logslot * 8;
        lp[q] = S + (isA ? 0 : 8192) + chunk * 512;
    }

    f32x4 acc[4][4];
    f32x4 zero = {0.0f, 0.0f, 0.0f, 0.0f};
#pragma unroll
    for (int i = 0; i < 4; ++i)
#pragma unroll
        for (int j = 0; j < 4; ++j) acc[i][j] = zero;

    const int wr = (w >> 1) * 64, wc = (w & 1) * 64;
    const int fr = ln & 15, kh = ln >> 4;
    const int fx = fr & 7;

    int aoff[2][4], boff[2][4];
#pragma unroll
    for (int kk = 0; kk < 2; ++kk)
#pragma unroll
        for (int mt = 0; mt < 4; ++mt) {
            aoff[kk][mt] = (wr + mt * 16 + fr) * 64 + (((kk << 2) | kh) ^ fx) * 8;
            boff[kk][mt] = (wc + mt * 16 + fr) * 64 + (((kk << 2) | kh) ^ fx) * 8;
        }

    const int np = NG / 64;  // 8

#pragma unroll
    for (int q = 0; q < 8; ++q) { gl_lds16(gp[q], lp[q]); gp[q] += 64; }
    asm volatile("s_waitcnt vmcnt(0)" ::: "memory");
    __builtin_amdgcn_s_barrier();
    __builtin_amdgcn_sched_barrier(0);

    int bi = 0;
    for (int p = 0; p < np; ++p) {
        if (p + 1 < np) {
#pragma unroll
            for (int q = 0; q < 8; ++q) {
                gl_lds16(gp[q], lp[q] + (bi ^ 1) * 16384);
                gp[q] += 64;
            }
        }
        const __bf16* As_ = S + bi * 16384;
        const __bf16* Bs_ = As_ + 8192;
        bf16x8 af[2][4], bf_[2][4];
#pragma unroll
        for (int kk = 0; kk < 2; ++kk) {
#pragma unroll
            for (int mt = 0; mt < 4; ++mt) af[kk][mt] = *(const bf16x8*)&As_[aoff[kk][mt]];
#pragma unroll
            for (int nt = 0; nt < 4; ++nt) bf_[kk][nt] = *(const bf16x8*)&Bs_[boff[kk][nt]];
        }
#pragma unroll
        for (int kk = 0; kk < 2; ++kk)
#pragma unroll
            for (int mt = 0; mt < 4; ++mt)
#pragma unroll
                for (int nt = 0; nt < 4; ++nt)
                    acc[mt][nt] = __builtin_amdgcn_mfma_f32_16x16x32_bf16(
                        af[kk][mt], bf_[kk][nt], acc[mt][nt], 0, 0, 0);
        asm volatile("s_waitcnt vmcnt(0)" ::: "memory");
        __builtin_amdgcn_s_barrier();
        __builtin_amdgcn_sched_barrier(0);
        bi ^= 1;
    }

    const float sc = 0.04419417382415922f;  // 1/sqrt(512)
    const int o = (col0 + wc) >> 6;         // wave-uniform
#pragma unroll
    for (int mt = 0; mt < 4; ++mt) {
#pragma unroll
        for (int e = 0; e < 4; ++e) {
            int c = row0 + wr + mt * 16 + kh * 4 + e;
            if (c < IDIM) {
                int l = 0;
#pragma unroll
                for (int ll = 1; ll < 11; ++ll)
                    if (c >= OFFS[ll]) l = ll;
                int d = 2 * l + 1, off = OFFS[l];
                int rem = c - off;
                int u = (unsigned)rem / (unsigned)d;
                int v = rem - u * d;
                __bf16* bb = Bm + (size_t)4096 * off + (size_t)(o * d + v) * (64 * d) + u * 64;
#pragma unroll
                for (int nt = 0; nt < 4; ++nt) {
                    int i = nt * 16 + fr;  // consecutive across 16-lane group
                    bb[i] = (__bf16)(acc[mt][nt][e] * sc);
                }
            }
        }
    }
}

// ---------------------------------------------------------------------------
// Merged stage-2 GEMM: BK=64 min-2-phase structure + XOR slot swizzle.
// Identical to the verified round-3 kernel (113 us, MfmaUtil 23%).
// ---------------------------------------------------------------------------
__global__ __launch_bounds__(256) void so3_gemm_all(const __bf16* __restrict__ A,
                                                    const __bf16* __restrict__ Bm,
                                                    float* __restrict__ out) {
    const int bid = blockIdx.x;
    const int v_ = (bid & 7) * 237 + (bid >> 3);  // grid 1896 = 8*237
    if (v_ >= 1892) return;

    int l = 10, base = 0;
    if (v_ >= 462)  { l = 9; base = 462; }
    if (v_ >= 842)  { l = 8; base = 842; }
    if (v_ >= 1148) { l = 7; base = 1148; }
    if (v_ >= 1388) { l = 6; base = 1388; }
    if (v_ >= 1570) { l = 5; base = 1570; }
    if (v_ >= 1702) { l = 4; base = 1702; }
    if (v_ >= 1792) { l = 3; base = 1792; }
    if (v_ >= 1848) { l = 2; base = 1848; }
    if (v_ >= 1878) { l = 1; base = 1878; }
    if (v_ >= 1890) { l = 0; base = 1890; }

    const int d = 2 * l + 1;
    const int off = OFFS[l];
    const int Np = 64 * d, Kp = 64 * d;
    const int ntiles = l + 1;
    const int rel = v_ - base;
    const int bx = (unsigned)rel / (unsigned)ntiles;
    const int by = rel - bx * ntiles;
    const int row0 = bx * 128, col0 = by * 128;

    constexpr float ALPHA[11] = {0.125f, 0.07216878f, 0.05590170f, 0.04724556f,
                                 0.04166667f, 0.03768892f, 0.03466879f, 0.03227486f,
                                 0.03031695f, 0.02867697f, 0.02727724f};

    __shared__ alignas(16) __bf16 S[2 * 16384];  // 64KB

    const int t = threadIdx.x, w = t >> 6, ln = t & 63;

    const __bf16* Abase = A + (size_t)16384 * off;
    const __bf16* Bbase = Bm + (size_t)4096 * off;

    const bool isA = (w < 2);
    const int wsub = w & 1;
    const int rowloc = ln >> 3;
    const int logslot = (ln & 7) ^ rowloc;

    const __bf16* gp[8];
    __bf16* lp[8];
#pragma unroll
    for (int q = 0; q < 8; ++q) {
        int chunk = wsub * 8 + q;
        int row = chunk * 8 + rowloc;
        int g = isA ? (row0 + row) : (col0 + row < Np ? col0 + row : Np - 1);
        gp[q] = (isA ? Abase : Bbase) + (size_t)g * Kp + logslot * 8;
        lp[q] = S + (isA ? 0 : 8192) + chunk * 512;
    }

    f32x4 acc[4][4];
    f32x4 zero = {0.0f, 0.0f, 0.0f, 0.0f};
#pragma unroll
    for (int i = 0; i < 4; ++i)
#pragma unroll
        for (int j = 0; j < 4; ++j) acc[i][j] = zero;

    const int wr = (w >> 1) * 64, wc = (w & 1) * 64;
    const int fr = ln & 15, kh = ln >> 4;
    const int fx = fr & 7;

    int aoff[2][4], boff[2][4];
#pragma unroll
    for (int kk = 0; kk < 2; ++kk)
#pragma unroll
        for (int mt = 0; mt < 4; ++mt) {
            aoff[kk][mt] = (wr + mt * 16 + fr) * 64 + (((kk << 2) | kh) ^ fx) * 8;
            boff[kk][mt] = (wc + mt * 16 + fr) * 64 + (((kk << 2) | kh) ^ fx) * 8;
        }

    const int np = Kp / 64;  // = d (1..21)

#pragma unroll
    for (int q = 0; q < 8; ++q) { gl_lds16(gp[q], lp[q]); gp[q] += 64; }
    asm volatile("s_waitcnt vmcnt(0)" ::: "memory");
    __builtin_amdgcn_s_barrier();
    __builtin_amdgcn_sched_barrier(0);

    int bi = 0;
    for (int p = 0; p < np; ++p) {
        if (p + 1 < np) {
#pragma unroll
            for (int q = 0; q < 8; ++q) {
                gl_lds16(gp[q], lp[q] + (bi ^ 1) * 16384);
                gp[q] += 64;
            }
        }
        const __bf16* As_ = S + bi * 16384;
        const __bf16* Bs_ = As_ + 8192;
        bf16x8 af[2][4], bf_[2][4];
#pragma unroll
        for (int kk = 0; kk < 2; ++kk) {
#pragma unroll
            for (int mt = 0; mt < 4; ++mt) af[kk][mt] = *(const bf16x8*)&As_[aoff[kk][mt]];
#pragma unroll
            for (int nt = 0; nt < 4; ++nt) bf_[kk][nt] = *(const bf16x8*)&Bs_[boff[kk][nt]];
        }
#pragma unroll
        for (int kk = 0; kk < 2; ++kk)
#pragma unroll
            for (int mt = 0; mt < 4; ++mt)
#pragma unroll
                for (int nt = 0; nt < 4; ++nt)
                    acc[mt][nt] = __builtin_amdgcn_mfma_f32_16x16x32_bf16(
                        af[kk][mt], bf_[kk][nt], acc[mt][nt], 0, 0, 0);
        asm volatile("s_waitcnt vmcnt(0)" ::: "memory");
        __builtin_amdgcn_s_barrier();
        __builtin_amdgcn_sched_barrier(0);
        bi ^= 1;
    }

    // ---- epilogue: per-wave LDS reorder so stores run contiguous along m ----
    __syncthreads();
    float* Tw = (float*)S + w * 256;  // 16x16 f32 per wave (1KB)
    const float alpha = ALPHA[l];

#pragma unroll
    for (int mt = 0; mt < 4; ++mt) {
        int r = row0 + wr + mt * 16 + fr;
        int b = (unsigned)r / (unsigned)d;
        int m = r - b * d;
        float* ob = out + (size_t)b * NF * IDIM + off + m;
#pragma unroll
        for (int nt = 0; nt < 4; ++nt) {
#pragma unroll
            for (int e = 0; e < 4; ++e) Tw[(kh * 4 + e) * 16 + fr] = acc[mt][nt][e];
            f32x4 vals = *(const f32x4*)&Tw[fr * 16 + kh * 4];
            int qb = col0 + wc + nt * 16 + kh * 4;
            int o = (unsigned)qb / (unsigned)d;
            int vv = qb - o * d;
#pragma unroll
            for (int j = 0; j < 4; ++j) {
                if (qb + j < Np) ob[o * IDIM + vv * d] = alpha * vals[j];
                ++vv;
                if (vv == d) { vv = 0; ++o; }
            }
        }
    }
}

// ---------------------------------------------------------------------------
extern "C" void kernel_launch(void* const* d_in, const int* in_sizes, int n_in,
                              void* d_out, int out_size, void* d_ws, size_t ws_size,
                              hipStream_t stream) {
    const float* x = (const float*)d_in[0];   // (256, 64, 1771)
    const float* D = (const float*)d_in[1];   // (512, 1771)
    const float* w = (const float*)d_in[2];   // (64, 64, 512)
    float* out = (float*)d_out;               // (256, 64, 1771)

    char* ws = (char*)d_ws;
    const size_t DT_BYTES = (size_t)IDIM * NG * 2;        // 1,813,504
    const size_t WB_BYTES = (size_t)4096 * NG * 2;        // 4,194,304
    const size_t A_BYTES = (size_t)16384 * IDIM * 2;      // 58,032,128

    __bf16* Dt = (__bf16*)ws;
    __bf16* wb = (__bf16*)(ws + DT_BYTES);
    __bf16* A = (__bf16*)(ws + DT_BYTES + WB_BYTES);
    __bf16* Bm = (__bf16*)(ws + DT_BYTES + WB_BYTES + A_BYTES);

    prep_repack_kernel<<<3104, 256, 0, stream>>>(D, w, x, Dt, wb, A);
    psi_mfma_kernel<<<dim3(14, 32), 256, 0, stream>>>(Dt, wb, Bm);
    so3_gemm_all<<<1896, 256, 0, stream>>>((const __bf16*)A, Bm, out);
}

// Round 9
// 367.845 us; speedup vs baseline: 1.1219x; 1.0226x over previous
//
#include <hip/hip_runtime.h>
#include <hip/hip_bf16.h>

#define IDIM 1771
#define NF 64
#define NG 512

constexpr int OFFS[12] = {0, 1, 10, 35, 84, 165, 286, 455, 680, 969, 1330, 1771};

typedef float f32x4 __attribute__((ext_vector_type(4)));
typedef float f32x2 __attribute__((ext_vector_type(2)));
typedef __bf16 bf16x2 __attribute__((ext_vector_type(2)));
typedef __bf16 bf16x8 __attribute__((ext_vector_type(8)));

__device__ __forceinline__ void gl_lds16(const void* g, void* l) {
    __builtin_amdgcn_global_load_lds((const __attribute__((address_space(1))) void*)g,
                                     (__attribute__((address_space(3))) void*)l, 16, 0, 0);
}

// ---------------------------------------------------------------------------
// Fused prep + repack (verified R7):
//  blk 0..223   : transpose D (512,1771) f32 -> Dt (1771,512) bf16
//  blk 224..287 : transpose-cast w[i][o][n] f32 -> wb[o][i][n] bf16
//  blk 288..3103: repack x -> A[r=b*d+m][k=u*64+i] bf16 (row-major, stride Kp)
// ---------------------------------------------------------------------------
__global__ __launch_bounds__(256) void prep_repack_kernel(const float* __restrict__ D,
                                                          const float* __restrict__ w,
                                                          const float* __restrict__ x,
                                                          __bf16* __restrict__ Dt,
                                                          __bf16* __restrict__ wb,
                                                          __bf16* __restrict__ A) {
    __shared__ alignas(16) char smem[16640];
    const int blk = blockIdx.x;
    const int t = threadIdx.x;
    const int lane = t & 63, grp = t >> 6;

    if (blk < 224) {
        float (*T)[65] = (float (*)[65])smem;
        const int ct = blk >> 3, nt = blk & 7;
        const int c0 = ct * 64, n0 = nt * 64;
        float tmp[16];
#pragma unroll
        for (int p = 0; p < 16; ++p) {
            int nn = grp + p * 4;
            int c = c0 + lane;
            tmp[p] = (c < IDIM) ? D[(size_t)(n0 + nn) * IDIM + c] : 0.0f;
        }
#pragma unroll
        for (int p = 0; p < 16; ++p) T[grp + p * 4][lane] = tmp[p];
        __syncthreads();
        for (int cc = grp; cc < 64; cc += 4) {
            int c = c0 + cc;
            if (c < IDIM) Dt[c * NG + n0 + lane] = (__bf16)T[lane][cc];
        }
    } else if (blk < 288) {
        const int o = blk - 224;
#pragma unroll
        for (int ii0 = 0; ii0 < 64; ii0 += 8) {
            f32x2 tmp[8];
#pragma unroll
            for (int j = 0; j < 8; ++j)
                tmp[j] = *(const f32x2*)&w[((size_t)((ii0 + j) * 64 + o)) * NG + t * 2];
#pragma unroll
            for (int j = 0; j < 8; ++j) {
                bf16x2 ov;
                ov.x = (__bf16)tmp[j].x;
                ov.y = (__bf16)tmp[j].y;
                *(bf16x2*)&wb[((size_t)(o * 64 + ii0 + j)) * NG + t * 2] = ov;
            }
        }
    } else {
        const int idx = blk - 288;
        const int l = idx >> 8;        // 0..10
        const int b = idx & 255;       // 0..255
        const int d = 2 * l + 1, off = OFFS[l], csq = d * d, Kp = 64 * d;
        __bf16 (*T)[66] = (__bf16 (*)[66])smem;  // [c=64][i=66 padded]
        const float* xb = x + (size_t)b * NF * IDIM + off;
        __bf16* Ab = A + (size_t)16384 * off + (size_t)b * d * Kp;

        for (int c0 = 0; c0 < csq; c0 += 64) {
            float tmp[16];
#pragma unroll
            for (int p = 0; p < 16; ++p) {
                int ii = grp * 16 + p;
                int c = c0 + lane;
                tmp[p] = (c < csq) ? xb[(size_t)ii * IDIM + c] : 0.0f;
            }
#pragma unroll
            for (int p2 = 0; p2 < 8; ++p2) {
                bf16x2 v;
                v.x = (__bf16)tmp[2 * p2];
                v.y = (__bf16)tmp[2 * p2 + 1];
                *(bf16x2*)&T[lane][grp * 16 + 2 * p2] = v;
            }
            __syncthreads();
#pragma unroll
            for (int s = 0; s < 2; ++s) {
                int idx2 = s * 256 + t;
                int c_loc = idx2 >> 3, i0 = (idx2 & 7) * 8;
                int c = c0 + c_loc;
                if (c < csq) {
                    int u = (unsigned)c / (unsigned)d;
                    int m = c - u * d;
                    bf16x8 v;
#pragma unroll
                    for (int j2 = 0; j2 < 4; ++j2) {
                        bf16x2 r = *(const bf16x2*)&T[c_loc][i0 + 2 * j2];
                        v[2 * j2] = r.x;
                        v[2 * j2 + 1] = r.y;
                    }
                    *(bf16x8*)(Ab + (size_t)m * Kp + u * 64 + i0) = v;
                }
            }
            __syncthreads();
        }
    }
}

// ---------------------------------------------------------------------------
// psi GEMM (verified R3/R7): BK=64, 2-stage dbuf, XOR slot swizzle.
// ---------------------------------------------------------------------------
__global__ __launch_bounds__(256) void psi_mfma_kernel(const __bf16* __restrict__ Dt,
                                                       const __bf16* __restrict__ wb,
                                                       __bf16* __restrict__ Bm) {
    __shared__ alignas(16) __bf16 S[2 * 16384];  // 64KB

    const int t = threadIdx.x, w = t >> 6, ln = t & 63;
    const int row0 = blockIdx.x * 128;  // c
    const int col0 = blockIdx.y * 128;  // io'

    const bool isA = (w < 2);
    const int wsub = w & 1;
    const int rowloc = ln >> 3;
    const int logslot = (ln & 7) ^ rowloc;

    const __bf16* gp[8];
    __bf16* lp[8];
#pragma unroll
    for (int q = 0; q < 8; ++q) {
        int chunk = wsub * 8 + q;
        int row = chunk * 8 + rowloc;
        int g = isA ? (row0 + row < IDIM ? row0 + row : IDIM - 1) : (col0 + row);
        gp[q] = (isA ? Dt : wb) + (size_t)g * NG + logslot * 8;
        lp[q] = S + (isA ? 0 : 8192) + chunk * 512;
    }

    f32x4 acc[4][4];
    f32x4 zero = {0.0f, 0.0f, 0.0f, 0.0f};
#pragma unroll
    for (int i = 0; i < 4; ++i)
#pragma unroll
        for (int j = 0; j < 4; ++j) acc[i][j] = zero;

    const int wr = (w >> 1) * 64, wc = (w & 1) * 64;
    const int fr = ln & 15, kh = ln >> 4;
    const int fx = fr & 7;

    int aoff[2][4], boff[2][4];
#pragma unroll
    for (int kk = 0; kk < 2; ++kk)
#pragma unroll
        for (int mt = 0; mt < 4; ++mt) {
            aoff[kk][mt] = (wr + mt * 16 + fr) * 64 + (((kk << 2) | kh) ^ fx) * 8;
            boff[kk][mt] = (wc + mt * 16 + fr) * 64 + (((kk << 2) | kh) ^ fx) * 8;
        }

    const int np = NG / 64;  // 8

#pragma unroll
    for (int q = 0; q < 8; ++q) { gl_lds16(gp[q], lp[q]); gp[q] += 64; }
    asm volatile("s_waitcnt vmcnt(0)" ::: "memory");
    __builtin_amdgcn_s_barrier();
    __builtin_amdgcn_sched_barrier(0);

    int bi = 0;
    for (int p = 0; p < np; ++p) {
        if (p + 1 < np) {
#pragma unroll
            for (int q = 0; q < 8; ++q) {
                gl_lds16(gp[q], lp[q] + (bi ^ 1) * 16384);
                gp[q] += 64;
            }
        }
        const __bf16* As_ = S + bi * 16384;
        const __bf16* Bs_ = As_ + 8192;
        bf16x8 af[2][4], bf_[2][4];
#pragma unroll
        for (int kk = 0; kk < 2; ++kk) {
#pragma unroll
            for (int mt = 0; mt < 4; ++mt) af[kk][mt] = *(const bf16x8*)&As_[aoff[kk][mt]];
#pragma unroll
            for (int nt = 0; nt < 4; ++nt) bf_[kk][nt] = *(const bf16x8*)&Bs_[boff[kk][nt]];
        }
#pragma unroll
        for (int kk = 0; kk < 2; ++kk)
#pragma unroll
            for (int mt = 0; mt < 4; ++mt)
#pragma unroll
                for (int nt = 0; nt < 4; ++nt)
                    acc[mt][nt] = __builtin_amdgcn_mfma_f32_16x16x32_bf16(
                        af[kk][mt], bf_[kk][nt], acc[mt][nt], 0, 0, 0);
        asm volatile("s_waitcnt vmcnt(0)" ::: "memory");
        __builtin_amdgcn_s_barrier();
        __builtin_amdgcn_sched_barrier(0);
        bi ^= 1;
    }

    const float sc = 0.04419417382415922f;  // 1/sqrt(512)
    const int o = (col0 + wc) >> 6;         // wave-uniform
#pragma unroll
    for (int mt = 0; mt < 4; ++mt) {
#pragma unroll
        for (int e = 0; e < 4; ++e) {
            int c = row0 + wr + mt * 16 + kh * 4 + e;
            if (c < IDIM) {
                int l = 0;
#pragma unroll
                for (int ll = 1; ll < 11; ++ll)
                    if (c >= OFFS[ll]) l = ll;
                int d = 2 * l + 1, off = OFFS[l];
                int rem = c - off;
                int u = (unsigned)rem / (unsigned)d;
                int v = rem - u * d;
                __bf16* bb = Bm + (size_t)4096 * off + (size_t)(o * d + v) * (64 * d) + u * 64;
#pragma unroll
                for (int nt = 0; nt < 4; ++nt) {
                    int i = nt * 16 + fr;
                    bb[i] = (__bf16)(acc[mt][nt][e] * sc);
                }
            }
        }
    }
}

// ---------------------------------------------------------------------------
// Stage-2 GEMM, 256x256 tile, 8 waves (512 thr), BK=64, 2-stage dbuf, XOR
// swizzle. Cuts LDS bytes/FLOP ~4x vs 128^2 (the measured bottleneck).
// Padded N tiles (N=64d -> ceil(d/4) tiles of 256): B rows clamped, garbage
// cols discarded by epilogue guard (same trick as verified 128^2 kernel).
// Grid = 506 virtual tiles, bijective XCD swizzle (506 = 8*63 + 2), l=10
// first so long blocks start early.
// ---------------------------------------------------------------------------
__global__ __launch_bounds__(512, 2) void so3_gemm_all(const __bf16* __restrict__ A,
                                                       const __bf16* __restrict__ Bm,
                                                       float* __restrict__ out) {
    // bijective XCD swizzle: nwg=506, q=63, r=2
    const int bid = blockIdx.x;
    const int xcd = bid & 7, sub = bid >> 3;
    const int v_ = (xcd < 2 ? xcd * 64 : 128 + (xcd - 2) * 63) + sub;

    int l = 10, base = 0;
    if (v_ >= 126) { l = 9; base = 126; }
    if (v_ >= 221) { l = 8; base = 221; }
    if (v_ >= 306) { l = 7; base = 306; }
    if (v_ >= 366) { l = 6; base = 366; }
    if (v_ >= 418) { l = 5; base = 418; }
    if (v_ >= 451) { l = 4; base = 451; }
    if (v_ >= 478) { l = 3; base = 478; }
    if (v_ >= 492) { l = 2; base = 492; }
    if (v_ >= 502) { l = 1; base = 502; }
    if (v_ >= 505) { l = 0; base = 505; }

    const int d = 2 * l + 1;
    const int off = OFFS[l];
    const int Np = 64 * d, Kp = 64 * d;
    const int nN = (d + 3) >> 2;  // ceil(d/4) 256-wide N tiles
    const int rel = v_ - base;
    const int bx = (unsigned)rel / (unsigned)nN;
    const int by = rel - bx * nN;
    const int row0 = bx * 256, col0 = by * 256;

    constexpr float ALPHA[11] = {0.125f, 0.07216878f, 0.05590170f, 0.04724556f,
                                 0.04166667f, 0.03768892f, 0.03466879f, 0.03227486f,
                                 0.03031695f, 0.02867697f, 0.02727724f};

    __shared__ alignas(16) __bf16 S[2 * 32768];  // 128KB: stage x (A 32KB | B 32KB)

    const int t = threadIdx.x, w = t >> 6, ln = t & 63;

    const __bf16* Abase = A + (size_t)16384 * off;
    const __bf16* Bbase = Bm + (size_t)4096 * off;

    // ---- staging: 8 issues/thread, 64KB/stage; XOR slot swizzle on source ----
    const int trow = t >> 3, tslot = t & 7;          // 64 rows x 8 slots per issue
    const int slog = tslot ^ (trow & 7);             // swizzled source k-slot
    const __bf16* gp[8];
    __bf16* lp[8];
#pragma unroll
    for (int q = 0; q < 8; ++q) {
        bool isA = q < 4;
        int rowblk = q & 3;
        int row = rowblk * 64 + trow;                // 0..255 within tile
        int g = isA ? (row0 + row) : (col0 + row < Np ? col0 + row : Np - 1);
        gp[q] = (isA ? Abase : Bbase) + (size_t)g * Kp + slog * 8;
        lp[q] = S + (isA ? 0 : 16384) + rowblk * 4096 + t * 8;  // linear: base + t*16B
    }

    f32x4 acc[8][4];
    f32x4 zero = {0.0f, 0.0f, 0.0f, 0.0f};
#pragma unroll
    for (int i = 0; i < 8; ++i)
#pragma unroll
        for (int j = 0; j < 4; ++j) acc[i][j] = zero;

    // ---- wave -> output subtile: 2M x 4N waves, each 128x64 ----
    const int wr = (w >> 2) * 128, wc = (w & 3) * 64;
    const int fr = ln & 15, kh = ln >> 4;
    const int fx = fr & 7;

    int aoff[2][8], boff[2][4];
#pragma unroll
    for (int kk = 0; kk < 2; ++kk) {
#pragma unroll
        for (int mt = 0; mt < 8; ++mt)
            aoff[kk][mt] = (wr + mt * 16 + fr) * 64 + (((kk << 2) | kh) ^ fx) * 8;
#pragma unroll
        for (int nt = 0; nt < 4; ++nt)
            boff[kk][nt] = (wc + nt * 16 + fr) * 64 + (((kk << 2) | kh) ^ fx) * 8;
    }

    const int np = d;  // K-steps of 64

    // prologue: stage buf0, drain, sync
#pragma unroll
    for (int q = 0; q < 8; ++q) { gl_lds16(gp[q], lp[q]); gp[q] += 64; }
    asm volatile("s_waitcnt vmcnt(0)" ::: "memory");
    __builtin_amdgcn_s_barrier();
    __builtin_amdgcn_sched_barrier(0);

    int bi = 0;
    for (int p = 0; p < np; ++p) {
        if (p + 1 < np) {
#pragma unroll
            for (int q = 0; q < 8; ++q) {
                gl_lds16(gp[q], lp[q] + (bi ^ 1) * 32768);
                gp[q] += 64;
            }
        }
        const __bf16* As_ = S + bi * 32768;
        const __bf16* Bs_ = As_ + 16384;
#pragma unroll
        for (int kk = 0; kk < 2; ++kk) {
            bf16x8 af[8], bfr[4];
#pragma unroll
            for (int mt = 0; mt < 8; ++mt) af[mt] = *(const bf16x8*)&As_[aoff[kk][mt]];
#pragma unroll
            for (int nt = 0; nt < 4; ++nt) bfr[nt] = *(const bf16x8*)&Bs_[boff[kk][nt]];
            __builtin_amdgcn_s_setprio(1);
#pragma unroll
            for (int mt = 0; mt < 8; ++mt)
#pragma unroll
                for (int nt = 0; nt < 4; ++nt)
                    acc[mt][nt] = __builtin_amdgcn_mfma_f32_16x16x32_bf16(
                        af[mt], bfr[nt], acc[mt][nt], 0, 0, 0);
            __builtin_amdgcn_s_setprio(0);
        }
        asm volatile("s_waitcnt vmcnt(0)" ::: "memory");
        __builtin_amdgcn_s_barrier();
        __builtin_amdgcn_sched_barrier(0);
        bi ^= 1;
    }

    // ---- epilogue: per-wave LDS reorder so stores run contiguous along m ----
    float* Tw = (float*)S + w * 256;  // 16x16 f32 per wave (8KB total)
    const float alpha = ALPHA[l];

#pragma unroll
    for (int mt = 0; mt < 8; ++mt) {
        int r = row0 + wr + mt * 16 + fr;
        int b = (unsigned)r / (unsigned)d;
        int m = r - b * d;
        float* ob = out + (size_t)b * NF * IDIM + off + m;
#pragma unroll
        for (int nt = 0; nt < 4; ++nt) {
#pragma unroll
            for (int e = 0; e < 4; ++e) Tw[(kh * 4 + e) * 16 + fr] = acc[mt][nt][e];
            f32x4 vals = *(const f32x4*)&Tw[fr * 16 + kh * 4];
            int qb = col0 + wc + nt * 16 + kh * 4;
            int o = (unsigned)qb / (unsigned)d;
            int vv = qb - o * d;
#pragma unroll
            for (int j = 0; j < 4; ++j) {
                if (qb + j < Np) ob[o * IDIM + vv * d] = alpha * vals[j];
                ++vv;
                if (vv == d) { vv = 0; ++o; }
            }
        }
    }
}

// ---------------------------------------------------------------------------
extern "C" void kernel_launch(void* const* d_in, const int* in_sizes, int n_in,
                              void* d_out, int out_size, void* d_ws, size_t ws_size,
                              hipStream_t stream) {
    const float* x = (const float*)d_in[0];   // (256, 64, 1771)
    const float* D = (const float*)d_in[1];   // (512, 1771)
    const float* w = (const float*)d_in[2];   // (64, 64, 512)
    float* out = (float*)d_out;               // (256, 64, 1771)

    char* ws = (char*)d_ws;
    const size_t DT_BYTES = (size_t)IDIM * NG * 2;        // 1,813,504
    const size_t WB_BYTES = (size_t)4096 * NG * 2;        // 4,194,304
    const size_t A_BYTES = (size_t)16384 * IDIM * 2;      // 58,032,128

    __bf16* Dt = (__bf16*)ws;
    __bf16* wb = (__bf16*)(ws + DT_BYTES);
    __bf16* A = (__bf16*)(ws + DT_BYTES + WB_BYTES);
    __bf16* Bm = (__bf16*)(ws + DT_BYTES + WB_BYTES + A_BYTES);

    prep_repack_kernel<<<3104, 256, 0, stream>>>(D, w, x, Dt, wb, A);
    psi_mfma_kernel<<<dim3(14, 32), 256, 0, stream>>>(Dt, wb, Bm);
    so3_gemm_all<<<506, 512, 0, stream>>>((const __bf16*)A, Bm, out);
}